// Round 1
// baseline (67.605 us; speedup 1.0000x reference)
//
#include <hip/hip_runtime.h>

#define RWIDTH 256
#define RHEIGHT 256
#define NUM_SAMPLES 64
#define HIDDEN 64
#define Z_NEAR 2.0f
#define Z_FAR 6.0f

// wave-per-ray, lane-per-sample.
// Layer-1 factorization: pre_h(t) = A_h * t + B_h (A,B computed once per ray).
__global__ __launch_bounds__(256) void render_kernel(
    const float* __restrict__ cam,    // 4x4 row-major
    const float* __restrict__ u,      // R x S
    const float* __restrict__ cdirs,  // R x 3
    const float* __restrict__ W1,     // 6 x 64 row-major
    const float* __restrict__ b1,     // 64
    const float* __restrict__ W2,     // 64 x 4 row-major
    const float* __restrict__ b2,     // 4
    float* __restrict__ out)          // R x 3
{
    const int lane = threadIdx.x & 63;
    const int wid  = threadIdx.x >> 6;
    const int ray  = blockIdx.x * 4 + wid;

    __shared__ float2 AB[4][HIDDEN];   // per-wave A,B pairs
    __shared__ float4 W2s[HIDDEN];     // shared by all waves in block

    if (threadIdx.x < HIDDEN) {
        const int h = threadIdx.x;
        W2s[h] = make_float4(W2[h*4+0], W2[h*4+1], W2[h*4+2], W2[h*4+3]);
    }

    // ray direction = rot(3x3) * cam_ray_dir ; origin = cam[:,3]
    const float cd0 = cdirs[ray*3+0], cd1 = cdirs[ray*3+1], cd2 = cdirs[ray*3+2];
    const float rd0 = fmaf(cam[0], cd0, fmaf(cam[1], cd1, cam[2]*cd2));
    const float rd1 = fmaf(cam[4], cd0, fmaf(cam[5], cd1, cam[6]*cd2));
    const float rd2 = fmaf(cam[8], cd0, fmaf(cam[9], cd1, cam[10]*cd2));
    const float o0 = cam[3], o1 = cam[7], o2 = cam[11];

    // per-hidden-unit affine coefficients, one lane per h
    {
        const int h = lane;
        const float w10 = W1[0*HIDDEN+h], w11 = W1[1*HIDDEN+h], w12 = W1[2*HIDDEN+h];
        const float w13 = W1[3*HIDDEN+h], w14 = W1[4*HIDDEN+h], w15 = W1[5*HIDDEN+h];
        const float A = fmaf(rd0, w10, fmaf(rd1, w11, rd2*w12));
        float B = fmaf(o0, w10, fmaf(o1, w11, o2*w12));
        B = fmaf(rd0, w13, fmaf(rd1, w14, fmaf(rd2, w15, B))) + b1[h];
        AB[wid][h] = make_float2(A, B);
    }
    __syncthreads();

    const float bin_dt = (Z_FAR - Z_NEAR) / (float)NUM_SAMPLES;
    const float uv = u[ray*NUM_SAMPLES + lane];            // coalesced
    const float t  = fmaf((float)lane + uv, bin_dt, Z_NEAR);
    const float t_next = __shfl_down(t, 1);
    const float sep = (lane < NUM_SAMPLES-1) ? (t_next - t) : bin_dt;

    // MLP: layer 1 affine-in-t + ReLU, layer 2 accumulate 4 outputs
    float acc0 = b2[0], acc1 = b2[1], acc2 = b2[2], acc3 = b2[3];
    #pragma unroll
    for (int h = 0; h < HIDDEN; ++h) {
        const float2 ab = AB[wid][h];                      // LDS broadcast
        const float act = fmaxf(fmaf(ab.x, t, ab.y), 0.0f);
        const float4 w2 = W2s[h];                          // LDS broadcast
        acc0 = fmaf(act, w2.x, acc0);
        acc1 = fmaf(act, w2.y, acc1);
        acc2 = fmaf(act, w2.z, acc2);
        acc3 = fmaf(act, w2.w, acc3);
    }

    // volume rendering composite
    const float density = fmaxf(acc0, 0.0f);
    const float alpha = 1.0f - __expf(-density * sep);
    const float om = 1.0f - alpha;

    // inclusive prefix product of (1-alpha) across lanes
    float P = om;
    #pragma unroll
    for (int off = 1; off < 64; off <<= 1) {
        const float v = __shfl_up(P, off);
        if (lane >= off) P *= v;
    }
    // exclusive transmittance
    float T = __shfl_up(P, 1);
    if (lane == 0) T = 1.0f;
    const float w = alpha * T;

    // weighted sigmoid colors, reduce across lanes
    float c0 = w / (1.0f + __expf(-acc1));
    float c1 = w / (1.0f + __expf(-acc2));
    float c2 = w / (1.0f + __expf(-acc3));
    #pragma unroll
    for (int off = 32; off >= 1; off >>= 1) {
        c0 += __shfl_xor(c0, off);
        c1 += __shfl_xor(c1, off);
        c2 += __shfl_xor(c2, off);
    }
    if (lane == 0) {
        out[ray*3+0] = c0;
        out[ray*3+1] = c1;
        out[ray*3+2] = c2;
    }
}

extern "C" void kernel_launch(void* const* d_in, const int* in_sizes, int n_in,
                              void* d_out, int out_size, void* d_ws, size_t ws_size,
                              hipStream_t stream) {
    const float* cam   = (const float*)d_in[0];
    const float* u     = (const float*)d_in[1];
    const float* cdirs = (const float*)d_in[2];
    const float* W1    = (const float*)d_in[3];
    const float* b1    = (const float*)d_in[4];
    const float* W2    = (const float*)d_in[5];
    const float* b2    = (const float*)d_in[6];
    float* out = (float*)d_out;

    const int R = RWIDTH * RHEIGHT;          // 65536 rays
    const int raysPerBlock = 4;              // 4 waves of 64
    dim3 grid(R / raysPerBlock), block(256);
    render_kernel<<<grid, block, 0, stream>>>(cam, u, cdirs, W1, b1, W2, b2, out);
}

// Round 3
// 41.876 us; speedup vs baseline: 1.6144x; 1.6144x over previous
//
#include <hip/hip_runtime.h>

#define NUM_SAMPLES 64
#define HIDDEN 64
#define Z_NEAR 2.0f
#define Z_FAR 6.0f

typedef _Float16 half8 __attribute__((ext_vector_type(8)));
typedef __fp16  fp16x2 __attribute__((ext_vector_type(2)));
typedef float float4t __attribute__((ext_vector_type(4)));

// wave-per-ray, lane-per-sample; layer-1 affine-in-t factorization (fp32);
// layer-2 64->4 via mfma_f32_16x16x32_f16 (4 M-tiles x 2 K-tiles per ray).
__global__ __launch_bounds__(256) void render_kernel(
    const float* __restrict__ cam,    // 4x4
    const float* __restrict__ u,      // R x S
    const float* __restrict__ cdirs,  // R x 3
    const float* __restrict__ W1,     // 6 x 64
    const float* __restrict__ b1,     // 64
    const float* __restrict__ W2,     // 64 x 4
    const float* __restrict__ b2,     // 4
    float* __restrict__ out)          // R x 3
{
    const int lane = threadIdx.x & 63;
    const int wid  = threadIdx.x >> 6;
    const int ray  = blockIdx.x * 4 + wid;
    const int grp  = lane >> 4;       // 16-lane group (k-group / C row group)
    const int col  = lane & 15;       // A row (sample-in-tile) / B,C col

    __shared__ __align__(16) float2 AB[4][HIDDEN]; // per-wave (A_h, B_h)
    __shared__ float  tsh[4][NUM_SAMPLES];
    __shared__ float4 W2s[HIDDEN];
    __shared__ float  cst[4][NUM_SAMPLES * 4];     // [wid][sample*4 + j]

    if (threadIdx.x < HIDDEN)
        W2s[threadIdx.x] = ((const float4*)W2)[threadIdx.x];

    // ray dir / origin
    const float cd0 = cdirs[ray*3+0], cd1 = cdirs[ray*3+1], cd2 = cdirs[ray*3+2];
    const float rd0 = fmaf(cam[0], cd0, fmaf(cam[1], cd1, cam[2]*cd2));
    const float rd1 = fmaf(cam[4], cd0, fmaf(cam[5], cd1, cam[6]*cd2));
    const float rd2 = fmaf(cam[8], cd0, fmaf(cam[9], cd1, cam[10]*cd2));
    const float o0 = cam[3], o1 = cam[7], o2 = cam[11];

    // per-hidden-unit affine coeffs: pre_h(t) = A_h*t + B_h ; lane h computes h=lane
    {
        const int h = lane;
        const float w10 = W1[0*HIDDEN+h], w11 = W1[1*HIDDEN+h], w12 = W1[2*HIDDEN+h];
        const float w13 = W1[3*HIDDEN+h], w14 = W1[4*HIDDEN+h], w15 = W1[5*HIDDEN+h];
        const float A = fmaf(rd0, w10, fmaf(rd1, w11, rd2*w12));
        float B = fmaf(o0, w10, fmaf(o1, w11, o2*w12));
        B = fmaf(rd0, w13, fmaf(rd1, w14, fmaf(rd2, w15, B))) + b1[h];
        AB[wid][lane] = make_float2(A, B);
    }

    const float bin_dt = (Z_FAR - Z_NEAR) / (float)NUM_SAMPLES;
    const float uv = u[ray*NUM_SAMPLES + lane];             // coalesced
    const float t  = fmaf((float)lane + uv, bin_dt, Z_NEAR);
    tsh[wid][lane] = t;
    const float t_next = __shfl_down(t, 1);
    const float sep = (lane < NUM_SAMPLES-1) ? (t_next - t) : bin_dt;

    __syncthreads();

    // hoisted AB coefficient loads for this lane's k-slots: h = kt*32 + grp*8 + j
    float4 abq[2][4];   // (A0,B0,A1,B1) per pair
    #pragma unroll
    for (int kt = 0; kt < 2; ++kt)
        #pragma unroll
        for (int q = 0; q < 4; ++q)
            abq[kt][q] = *(const float4*)(&AB[wid][kt*32 + grp*8 + q*2]);

    // B-fragment: B[k][col] = W2[h][col], zero for col>=4
    half8 bfrag[2];
    #pragma unroll
    for (int kt = 0; kt < 2; ++kt) {
        union { fp16x2 h2[4]; half8 h8; } bu;
        #pragma unroll
        for (int q = 0; q < 4; ++q) {
            const int h0 = kt*32 + grp*8 + q*2;
            float v0 = 0.0f, v1 = 0.0f;
            if (col < 4) {
                v0 = ((const float*)&W2s[h0  ])[col];
                v1 = ((const float*)&W2s[h0+1])[col];
            }
            bu.h2[q] = __builtin_amdgcn_cvt_pkrtz(v0, v1);
        }
        bfrag[kt] = bu.h8;
    }

    // 4 M-tiles of 16 samples; per tile: build A-frag (relu affine) + 2 MFMA
    #pragma unroll
    for (int m = 0; m < 4; ++m) {
        const float tm = tsh[wid][col + 16*m];
        float4t c = {0.f, 0.f, 0.f, 0.f};
        #pragma unroll
        for (int kt = 0; kt < 2; ++kt) {
            union { fp16x2 h2[4]; half8 h8; } au;
            #pragma unroll
            for (int q = 0; q < 4; ++q) {
                const float4 abv = abq[kt][q];
                const float a0 = fmaxf(fmaf(abv.x, tm, abv.y), 0.0f);
                const float a1 = fmaxf(fmaf(abv.z, tm, abv.w), 0.0f);
                au.h2[q] = __builtin_amdgcn_cvt_pkrtz(a0, a1);
            }
            c = __builtin_amdgcn_mfma_f32_16x16x32_f16(au.h8, bfrag[kt], c, 0, 0, 0);
        }
        if (col < 4) {
            #pragma unroll
            for (int r = 0; r < 4; ++r) {
                const int sample = 16*m + grp*4 + r;
                cst[wid][sample*4 + col] = c[r];
            }
        }
    }

    __syncthreads();

    // read back this lane's sample outputs
    const float4 a4 = *(const float4*)(&cst[wid][lane*4]);
    const float acc0 = a4.x + b2[0];
    const float acc1 = a4.y + b2[1];
    const float acc2 = a4.z + b2[2];
    const float acc3 = a4.w + b2[3];

    // volume rendering composite
    const float density = fmaxf(acc0, 0.0f);
    const float alpha = 1.0f - __expf(-density * sep);
    const float om = 1.0f - alpha;

    float P = om;
    #pragma unroll
    for (int off = 1; off < 64; off <<= 1) {
        const float v = __shfl_up(P, off);
        if (lane >= off) P *= v;
    }
    float T = __shfl_up(P, 1);
    if (lane == 0) T = 1.0f;
    const float w = alpha * T;

    float c0 = w * __builtin_amdgcn_rcpf(1.0f + __expf(-acc1));
    float c1 = w * __builtin_amdgcn_rcpf(1.0f + __expf(-acc2));
    float c2 = w * __builtin_amdgcn_rcpf(1.0f + __expf(-acc3));
    #pragma unroll
    for (int off = 32; off >= 1; off >>= 1) {
        c0 += __shfl_xor(c0, off);
        c1 += __shfl_xor(c1, off);
        c2 += __shfl_xor(c2, off);
    }
    if (lane == 0) {
        out[ray*3+0] = c0;
        out[ray*3+1] = c1;
        out[ray*3+2] = c2;
    }
}

extern "C" void kernel_launch(void* const* d_in, const int* in_sizes, int n_in,
                              void* d_out, int out_size, void* d_ws, size_t ws_size,
                              hipStream_t stream) {
    const float* cam   = (const float*)d_in[0];
    const float* u     = (const float*)d_in[1];
    const float* cdirs = (const float*)d_in[2];
    const float* W1    = (const float*)d_in[3];
    const float* b1    = (const float*)d_in[4];
    const float* W2    = (const float*)d_in[5];
    const float* b2    = (const float*)d_in[6];
    float* out = (float*)d_out;

    const int R = 256 * 256;
    dim3 grid(R / 4), block(256);
    render_kernel<<<grid, block, 0, stream>>>(cam, u, cdirs, W1, b1, W2, b2, out);
}